// Round 12
// baseline (117.281 us; speedup 1.0000x reference)
//
#include <hip/hip_runtime.h>

#define CC 30                      // 5*NB + NC
#define TPW 32                     // cells per wave-tile (lane-paired compute keeps 64 lanes busy)
#define WPB 4                      // waves per block (256-thread blocks)
#define TILE_FLOATS (TPW * CC)     // 960 floats = 3840 B per array per wave
#define TILE_VEC4   (TILE_FLOATS / 4)   // 240 float4 per array

#define AS1 __attribute__((address_space(1)))
#define AS3 __attribute__((address_space(3)))

// async 16B/lane DMA: lane i of the wave writes lds_base + i*16 (wave-uniform dst)
__device__ __forceinline__ void dma16(const float4* gsrc_lane, float4* lds_base) {
    __builtin_amdgcn_global_load_lds((const AS1 unsigned int*)gsrc_lane,
                                     (AS3 unsigned int*)lds_base, 16, 0, 0);
}

// Issue DMA for one 32-cell tile: 240 float4 per array = 3 full chunks + 48-lane tail,
// both arrays -> exactly 8 vmem instructions, no VGPR payload.
__device__ __forceinline__ void prefetch_tile(const float* __restrict__ in,
                                              const float* __restrict__ tg,
                                              size_t cell_base,   // multiple of 32 -> 16B-aligned
                                              float* lin, float* ltg, int lane) {
    const float4* gin = (const float4*)(in + cell_base * CC);
    const float4* gtg = (const float4*)(tg + cell_base * CC);
    float4* vin = (float4*)lin;
    float4* vtg = (float4*)ltg;
    #pragma unroll
    for (int k = 0; k < 3; ++k) {
        dma16(gin + k * 64 + lane, vin + k * 64);
        dma16(gtg + k * 64 + lane, vtg + k * 64);
    }
    if (lane < 48) {                       // float4 idx 192..239
        dma16(gin + 192 + lane, vin + 192);
        dma16(gtg + 192 + lane, vtg + 192);
    }
}

// ---- 32 cells with 64 lanes: lane 2c+h owns cell c's predicted box h (verified R11) ----
__device__ __forceinline__ void compute_tile(const float* __restrict__ lin,
                                             const float* __restrict__ ltg,
                                             int lane, float inv_gs,
                                             float& a_boxes, float& a_conf, float& a_class) {
    const int c = lane >> 1;
    const int h = lane & 1;
    const float* f = lin + c * CC;
    const float* t = ltg + c * CC;

    // own predicted box (h=0: f[0..4], h=1: f[5..9])
    const int hb = 5 * h;
    const float px  = f[hb + 0];
    const float py  = f[hb + 1];
    const float pw  = f[hb + 2];
    const float phh = f[hb + 3];
    const float pc  = f[hb + 4];

    // target box + confidences (pair-broadcast reads are conflict-free)
    const float bt0 = t[0], bt1 = t[1], bt2 = t[2], bt3 = t[3];
    const float conf_t  = t[4];
    const float tconf_h = t[hb + 4];               // t[4] or t[9]
    const float coord = (conf_t > 0.0f)  ? 1.0f : 0.0f;
    const float noobj = (conf_t == 0.0f) ? 1.0f : 0.0f;

    // noobj split across the pair: lane h does (f[5h+4]-t[5h+4])^2
    const float dn = pc - tconf_h;

    // target corners
    const float ttx = bt0 * inv_gs, tty = bt1 * inv_gs;
    const float txmin = ttx - 0.5f * bt2, tymin = tty - 0.5f * bt3;
    const float txmax = ttx + 0.5f * bt2, tymax = tty + 0.5f * bt3;
    const float tarea = (txmax - txmin) * (tymax - tymin);

    // own IOU
    const float cx = px * inv_gs, cy = py * inv_gs;
    const float xmin = cx - 0.5f * pw, ymin = cy - 0.5f * phh;
    const float xmax = cx + 0.5f * pw, ymax = cy + 0.5f * phh;
    const float wx = fmaxf(fminf(xmax, txmax) - fmaxf(xmin, txmin), 0.0f);
    const float wy = fmaxf(fminf(ymax, tymax) - fmaxf(ymin, tymin), 0.0f);
    const float inter = wx * wy;
    const float parea = (xmax - xmin) * (ymax - ymin);
    const float iou_mine = inter / (parea + tarea - inter);

    // pair exchange
    const float iou_other = __shfl_xor(iou_mine, 1, 64);
    const float iou0 = h ? iou_other : iou_mine;
    const float iou1 = h ? iou_mine  : iou_other;
    const bool  sel1 = iou1 > iou0;            // jnp.argmax: first max on ties
    const float max_iou = fmaxf(iou0, iou1);
    const float own = ((h == 1) == sel1) ? 1.0f : 0.0f;

    const float dx = px - bt0, dy = py - bt1;
    const float sw = sqrtf(pw)  - sqrtf(bt2);
    const float sh = sqrtf(phh) - sqrtf(bt3);
    const float dob = pc - max_iou;

    a_boxes += own * coord * (dx * dx + dy * dy + sw * sw + sh * sh);
    a_conf  += own * coord * (dob * dob) + 0.5f * noobj * dn * dn;

    // class loss split: lane h handles float2 idx 5+5h .. 9+5h (10 channels)
    const float2* f2 = (const float2*)f;
    const float2* t2 = (const float2*)t;
    float l = 0.0f;
    #pragma unroll
    for (int j = 0; j < 5; ++j) {
        const float2 fv = f2[5 + 5 * h + j];
        const float2 tv = t2[5 + 5 * h + j];
        const float gx = fv.x - tv.x;
        const float gy = fv.y - tv.y;
        l += gx * gx + gy * gy;
    }
    a_class += coord * l;
}

// ---- scalar path (global pointers) for the <32-cell remainder, used in finalize ----
__device__ __forceinline__ void cell_losses_global(const float* __restrict__ f,
                                                   const float* __restrict__ t,
                                                   float& o_boxes, float& o_conf, float& o_cls) {
    const float inv_gs = 0.14285714285714285f;
    const float conf_t = t[4];
    const float coord  = (conf_t > 0.0f)  ? 1.0f : 0.0f;
    const float noobj  = (conf_t == 0.0f) ? 1.0f : 0.0f;
    const float d0 = f[4] - t[4];
    const float d1 = f[9] - t[9];
    const float l_noobj = noobj * (d0 * d0 + d1 * d1);
    const float bt0 = t[0], bt1 = t[1], bt2 = t[2], bt3 = t[3];
    const float ttx = bt0 * inv_gs, tty = bt1 * inv_gs;
    const float txmin = ttx - 0.5f * bt2, tymin = tty - 0.5f * bt3;
    const float txmax = ttx + 0.5f * bt2, tymax = tty + 0.5f * bt3;
    const float tarea = (txmax - txmin) * (tymax - tymin);
    float iou0, iou1;
    {
        const float cx = f[0] * inv_gs, cy = f[1] * inv_gs;
        const float xmin = cx - 0.5f * f[2], ymin = cy - 0.5f * f[3];
        const float xmax = cx + 0.5f * f[2], ymax = cy + 0.5f * f[3];
        const float wx = fmaxf(fminf(xmax, txmax) - fmaxf(xmin, txmin), 0.0f);
        const float wy = fmaxf(fminf(ymax, tymax) - fmaxf(ymin, tymin), 0.0f);
        const float inter = wx * wy;
        const float parea = (xmax - xmin) * (ymax - ymin);
        iou0 = inter / (parea + tarea - inter);
    }
    {
        const float cx = f[5] * inv_gs, cy = f[6] * inv_gs;
        const float xmin = cx - 0.5f * f[7], ymin = cy - 0.5f * f[8];
        const float xmax = cx + 0.5f * f[7], ymax = cy + 0.5f * f[8];
        const float wx = fmaxf(fminf(xmax, txmax) - fmaxf(xmin, txmin), 0.0f);
        const float wy = fmaxf(fminf(ymax, tymax) - fmaxf(ymin, tymin), 0.0f);
        const float inter = wx * wy;
        const float parea = (xmax - xmin) * (ymax - ymin);
        iou1 = inter / (parea + tarea - inter);
    }
    const bool  sel1    = iou1 > iou0;
    const float max_iou = fmaxf(iou0, iou1);
    const float rp0 = sel1 ? f[5] : f[0];
    const float rp1 = sel1 ? f[6] : f[1];
    const float rp2 = sel1 ? f[7] : f[2];
    const float rp3 = sel1 ? f[8] : f[3];
    const float rp4 = sel1 ? f[9] : f[4];
    const float dx = rp0 - bt0, dy = rp1 - bt1;
    const float sw = sqrtf(rp2) - sqrtf(bt2);
    const float sh = sqrtf(rp3) - sqrtf(bt3);
    const float dob = rp4 - max_iou;
    float l_cls = 0.0f;
    #pragma unroll
    for (int j = 10; j < 30; ++j) {
        const float d = f[j] - t[j];
        l_cls += d * d;
    }
    o_boxes += coord * (dx * dx + dy * dy + sw * sw + sh * sh);
    o_conf  += coord * (dob * dob) + 0.5f * l_noobj;
    o_cls   += coord * l_cls;
}

// ------- main: R10 skeleton (single-buffer DMA, full drain) at TPW=32, 20 waves/CU -------
__global__ __launch_bounds__(256) void yolo_main(
        const float* __restrict__ in,
        const float* __restrict__ tg,
        float* __restrict__ ws,
        int ncells, int nwaves_total, int pstride) {
    // per wave: in 960 + tg 960 floats = 7680 B; x4 waves = 30720 B -> 5 blocks/CU
    __shared__ float s_lds[WPB * 2 * TILE_FLOATS];

    const int tid   = threadIdx.x;
    const int lane  = tid & 63;
    const int wave  = tid >> 6;
    const int gwave = blockIdx.x * WPB + wave;

    float* lin = s_lds + wave * (2 * TILE_FLOATS);
    float* ltg = lin + TILE_FLOATS;

    const int ntiles = ncells / TPW;            // full 32-cell tiles (remainder -> finalize)
    const float inv_gs = 0.14285714285714285f;  // 1/7 (abs err ~1e-7 vs 0.4 threshold)

    float a_boxes = 0.0f, a_conf = 0.0f, a_class = 0.0f;

    for (int t = gwave; t < ntiles; t += nwaves_total) {
        // prior tile's ds_reads must retire before DMA overwrites this wave's buffer
        asm volatile("s_waitcnt lgkmcnt(0)" ::: "memory");
        __builtin_amdgcn_wave_barrier();
        prefetch_tile(in, tg, (size_t)t * TPW, lin, ltg, lane);   // 8 async DMAs
        asm volatile("s_waitcnt vmcnt(0)" ::: "memory");
        __builtin_amdgcn_wave_barrier();
        compute_tile(lin, ltg, lane, inv_gs, a_boxes, a_conf, a_class);
        __builtin_amdgcn_wave_barrier();
    }

    // ---- wave-64 shuffle reduce; one partial triple per WAVE ----
    #pragma unroll
    for (int off = 32; off > 0; off >>= 1) {
        a_boxes += __shfl_down(a_boxes, off, 64);
        a_conf  += __shfl_down(a_conf,  off, 64);
        a_class += __shfl_down(a_class, off, 64);
    }
    if (lane == 0) {
        ws[gwave]               = a_boxes;
        ws[gwave + pstride]     = a_conf;
        ws[gwave + 2 * pstride] = a_class;
    }
}

// ---------------- finalize: sum per-wave partials + remainder cells, scale, write out ----------------
__global__ __launch_bounds__(256) void yolo_finalize(
        const float* __restrict__ in,
        const float* __restrict__ tg,
        const float* __restrict__ ws, float* __restrict__ out,
        int nparts, int pstride, int rem_base, int rem, float inv_bs) {
    float b = 0.0f, c = 0.0f, k = 0.0f;
    for (int i = threadIdx.x; i < nparts; i += 256) {
        b += ws[i];
        c += ws[i + pstride];
        k += ws[i + 2 * pstride];
    }
    if ((int)threadIdx.x < rem) {
        const size_t cell = (size_t)(rem_base + threadIdx.x) * CC;
        cell_losses_global(in + cell, tg + cell, b, c, k);
    }
    #pragma unroll
    for (int off = 32; off > 0; off >>= 1) {
        b += __shfl_down(b, off, 64);
        c += __shfl_down(c, off, 64);
        k += __shfl_down(k, off, 64);
    }
    __shared__ float s_red[4][3];
    const int wave = threadIdx.x >> 6;
    if ((threadIdx.x & 63) == 0) {
        s_red[wave][0] = b;
        s_red[wave][1] = c;
        s_red[wave][2] = k;
    }
    __syncthreads();
    if (threadIdx.x == 0) {
        const float tb = s_red[0][0] + s_red[1][0] + s_red[2][0] + s_red[3][0];
        const float tc = s_red[0][1] + s_red[1][1] + s_red[2][1] + s_red[3][1];
        const float tk = s_red[0][2] + s_red[1][2] + s_red[2][2] + s_red[3][2];
        out[0] = 0.5f * tb * inv_bs;   // LAMBDA_COORD*(xy+wh)/bs
        out[1] = tc * inv_bs;          // (obj + 0.5*noobj)/bs
        out[2] = tk * inv_bs;          // class/bs
    }
}

extern "C" void kernel_launch(void* const* d_in, const int* in_sizes, int n_in,
                              void* d_out, int out_size, void* d_ws, size_t ws_size,
                              hipStream_t stream) {
    const float* in = (const float*)d_in[0];
    const float* tg = (const float*)d_in[1];
    float* out = (float*)d_out;
    float* ws  = (float*)d_ws;

    const int ncells = in_sizes[0] / CC;          // B * 49
    const int B = ncells / 49;
    const float inv_bs = 1.0f / (float)B;

    // 30.7 KB LDS/block -> 5 blocks/CU = 20 waves/CU; 1280 blocks co-resident.
    const int nblocks = 1280;
    const int nwaves  = nblocks * WPB;            // 5120
    const int pstride = nwaves;
    const int ntiles  = ncells / TPW;
    const int rem     = ncells - ntiles * TPW;    // 0 at B=8192

    yolo_main<<<nblocks, 256, 0, stream>>>(in, tg, ws, ncells, nwaves, pstride);
    yolo_finalize<<<1, 256, 0, stream>>>(in, tg, ws, out, nwaves, pstride,
                                         ntiles * TPW, rem, inv_bs);
}

// Round 13
// 111.481 us; speedup vs baseline: 1.0520x; 1.0520x over previous
//
#include <hip/hip_runtime.h>

#define CC 30                    // 5*NB + NC
#define TPW 64                   // cells per wave-tile (full wave active in compute)
#define WPB 4                    // waves per block (256-thread blocks)
#define TILE_FLOATS (TPW * CC)   // 1920 floats = 7680 B per array
#define TILE_VEC4   (TILE_FLOATS / 4)   // 480

#define AS1 __attribute__((address_space(1)))
#define AS3 __attribute__((address_space(3)))

// async 16B/lane DMA: lane i of the wave writes lds_base + i*16 (wave-uniform dst)
__device__ __forceinline__ void dma16(const float4* gsrc_lane, float4* lds_base) {
    __builtin_amdgcn_global_load_lds((const AS1 unsigned int*)gsrc_lane,
                                     (AS3 unsigned int*)lds_base, 16, 0, 0);
}

// Issue all DMA for one tile (480 float4 per array = 7 full-wave chunks + half chunk).
__device__ __forceinline__ void prefetch_tile(const float* __restrict__ in,
                                              const float* __restrict__ tg,
                                              int t, float* lin, float* ltg, int lane) {
    const float4* gin = (const float4*)(in + (size_t)t * TILE_FLOATS);
    const float4* gtg = (const float4*)(tg + (size_t)t * TILE_FLOATS);
    float4* vin = (float4*)lin;
    float4* vtg = (float4*)ltg;
    #pragma unroll
    for (int k = 0; k < 7; ++k) {
        dma16(gin + k * 64 + lane, vin + k * 64);
        dma16(gtg + k * 64 + lane, vtg + k * 64);
    }
    if (lane < 32) {                      // tail: float4 idx 448..479
        dma16(gin + 448 + lane, vin + 448);
        dma16(gtg + 448 + lane, vtg + 448);
    }
}

// ---- per-cell losses from LDS, cell = lane, float2 reads (8B-aligned @120B records) ----
__device__ __forceinline__ void compute_tile(const float* __restrict__ lin,
                                             const float* __restrict__ ltg,
                                             int lane, float inv_gs,
                                             float& a_boxes, float& a_conf, float& a_class) {
    const float2* f2 = (const float2*)(lin + lane * CC);
    const float2* t2 = (const float2*)(ltg + lane * CC);

    const float2 fi0 = f2[0], fi1 = f2[1], fi2 = f2[2], fi3 = f2[3], fi4 = f2[4];
    const float2 tt0 = t2[0], tt1 = t2[1], tt2 = t2[2], tt4 = t2[4];

    const float conf_t = tt2.x;                  // t[4]
    const float coord  = (conf_t > 0.0f)  ? 1.0f : 0.0f;
    const float noobj  = (conf_t == 0.0f) ? 1.0f : 0.0f;

    const float d0 = fi2.x - tt2.x;              // f[4]-t[4]
    const float d1 = fi4.y - tt4.y;              // f[9]-t[9]
    const float l_noobj = noobj * (d0 * d0 + d1 * d1);

    const float bt0 = tt0.x, bt1 = tt0.y, bt2 = tt1.x, bt3 = tt1.y;
    const float ttx = bt0 * inv_gs, tty = bt1 * inv_gs;
    const float txmin = ttx - 0.5f * bt2, tymin = tty - 0.5f * bt3;
    const float txmax = ttx + 0.5f * bt2, tymax = tty + 0.5f * bt3;
    const float tarea = (txmax - txmin) * (tymax - tymin);

    const float px0 = fi0.x, py0 = fi0.y, pw0 = fi1.x, ph0 = fi1.y, pc0 = fi2.x;
    const float px1 = fi2.y, py1 = fi3.x, pw1 = fi3.y, ph1 = fi4.x, pc1 = fi4.y;

    float iou0, iou1;
    {
        const float cx = px0 * inv_gs, cy = py0 * inv_gs;
        const float xmin = cx - 0.5f * pw0, ymin = cy - 0.5f * ph0;
        const float xmax = cx + 0.5f * pw0, ymax = cy + 0.5f * ph0;
        const float wx = fmaxf(fminf(xmax, txmax) - fmaxf(xmin, txmin), 0.0f);
        const float wy = fmaxf(fminf(ymax, tymax) - fmaxf(ymin, tymin), 0.0f);
        const float inter = wx * wy;
        const float parea = (xmax - xmin) * (ymax - ymin);
        iou0 = inter / (parea + tarea - inter);
    }
    {
        const float cx = px1 * inv_gs, cy = py1 * inv_gs;
        const float xmin = cx - 0.5f * pw1, ymin = cy - 0.5f * ph1;
        const float xmax = cx + 0.5f * pw1, ymax = cy + 0.5f * ph1;
        const float wx = fmaxf(fminf(xmax, txmax) - fmaxf(xmin, txmin), 0.0f);
        const float wy = fmaxf(fminf(ymax, tymax) - fmaxf(ymin, tymin), 0.0f);
        const float inter = wx * wy;
        const float parea = (xmax - xmin) * (ymax - ymin);
        iou1 = inter / (parea + tarea - inter);
    }
    // jnp.argmax picks first max on ties -> strict > for box 1
    const bool  sel1    = iou1 > iou0;
    const float max_iou = fmaxf(iou0, iou1);

    const float rp0 = sel1 ? px1 : px0;
    const float rp1 = sel1 ? py1 : py0;
    const float rp2 = sel1 ? pw1 : pw0;
    const float rp3 = sel1 ? ph1 : ph0;
    const float rp4 = sel1 ? pc1 : pc0;

    const float dx = rp0 - bt0, dy = rp1 - bt1;
    const float sw = sqrtf(rp2) - sqrtf(bt2);
    const float sh = sqrtf(rp3) - sqrtf(bt3);
    const float dob = rp4 - max_iou;
    const float l_box = dx * dx + dy * dy + sw * sw + sh * sh;
    const float l_obj = dob * dob;

    float l_cls = 0.0f;
    #pragma unroll
    for (int j = 5; j < 15; ++j) {         // channels 10..29 = float2 idx 5..14
        const float2 fv = f2[j];
        const float2 tv = t2[j];
        const float gx = fv.x - tv.x;
        const float gy = fv.y - tv.y;
        l_cls += gx * gx + gy * gy;
    }

    a_boxes += coord * l_box;
    a_conf  += coord * l_obj + 0.5f * l_noobj;
    a_class += coord * l_cls;
}

// ---- scalar path (global pointers) for the <64-cell remainder, used in finalize ----
__device__ __forceinline__ void cell_losses_global(const float* __restrict__ f,
                                                   const float* __restrict__ t,
                                                   float& o_boxes, float& o_conf, float& o_cls) {
    const float inv_gs = 0.14285714285714285f;
    const float conf_t = t[4];
    const float coord  = (conf_t > 0.0f)  ? 1.0f : 0.0f;
    const float noobj  = (conf_t == 0.0f) ? 1.0f : 0.0f;
    const float d0 = f[4] - t[4];
    const float d1 = f[9] - t[9];
    const float l_noobj = noobj * (d0 * d0 + d1 * d1);
    const float bt0 = t[0], bt1 = t[1], bt2 = t[2], bt3 = t[3];
    const float ttx = bt0 * inv_gs, tty = bt1 * inv_gs;
    const float txmin = ttx - 0.5f * bt2, tymin = tty - 0.5f * bt3;
    const float txmax = ttx + 0.5f * bt2, tymax = tty + 0.5f * bt3;
    const float tarea = (txmax - txmin) * (tymax - tymin);
    float iou0, iou1;
    {
        const float cx = f[0] * inv_gs, cy = f[1] * inv_gs;
        const float xmin = cx - 0.5f * f[2], ymin = cy - 0.5f * f[3];
        const float xmax = cx + 0.5f * f[2], ymax = cy + 0.5f * f[3];
        const float wx = fmaxf(fminf(xmax, txmax) - fmaxf(xmin, txmin), 0.0f);
        const float wy = fmaxf(fminf(ymax, tymax) - fmaxf(ymin, tymin), 0.0f);
        const float inter = wx * wy;
        const float parea = (xmax - xmin) * (ymax - ymin);
        iou0 = inter / (parea + tarea - inter);
    }
    {
        const float cx = f[5] * inv_gs, cy = f[6] * inv_gs;
        const float xmin = cx - 0.5f * f[7], ymin = cy - 0.5f * f[8];
        const float xmax = cx + 0.5f * f[7], ymax = cy + 0.5f * f[8];
        const float wx = fmaxf(fminf(xmax, txmax) - fmaxf(xmin, txmin), 0.0f);
        const float wy = fmaxf(fminf(ymax, tymax) - fmaxf(ymin, tymin), 0.0f);
        const float inter = wx * wy;
        const float parea = (xmax - xmin) * (ymax - ymin);
        iou1 = inter / (parea + tarea - inter);
    }
    const bool  sel1    = iou1 > iou0;
    const float max_iou = fmaxf(iou0, iou1);
    const float rp0 = sel1 ? f[5] : f[0];
    const float rp1 = sel1 ? f[6] : f[1];
    const float rp2 = sel1 ? f[7] : f[2];
    const float rp3 = sel1 ? f[8] : f[3];
    const float rp4 = sel1 ? f[9] : f[4];
    const float dx = rp0 - bt0, dy = rp1 - bt1;
    const float sw = sqrtf(rp2) - sqrtf(bt2);
    const float sh = sqrtf(rp3) - sqrtf(bt3);
    const float dob = rp4 - max_iou;
    float l_cls = 0.0f;
    #pragma unroll
    for (int j = 10; j < 30; ++j) {
        const float d = f[j] - t[j];
        l_cls += d * d;
    }
    o_boxes += coord * (dx * dx + dy * dy + sw * sw + sh * sh);
    o_conf  += coord * (dob * dob) + 0.5f * l_noobj;
    o_cls   += coord * l_cls;
}

// ---------------- main: wave-private single-buffer LDS + async DMA, 8 waves/CU ----------------
__global__ __launch_bounds__(256) void yolo_main(
        const float* __restrict__ in,
        const float* __restrict__ tg,
        float* __restrict__ ws,
        int ncells, int nwaves_total, int pstride) {
    // per wave: in 1920 + tg 1920 floats = 15360 B; x4 waves = 61440 B
    __shared__ float s_lds[WPB * 2 * TILE_FLOATS];

    const int tid   = threadIdx.x;
    const int lane  = tid & 63;
    const int wave  = tid >> 6;
    const int gwave = blockIdx.x * WPB + wave;

    float* lin = s_lds + wave * (2 * TILE_FLOATS);
    float* ltg = lin + TILE_FLOATS;

    const int nfull = ncells / TPW;             // full tiles only (remainder -> finalize)
    const float inv_gs = 0.14285714285714285f;  // 1/7 (abs err ~1e-7 vs 0.4 threshold)

    float a_boxes = 0.0f, a_conf = 0.0f, a_class = 0.0f;

    for (int t = gwave; t < nfull; t += nwaves_total) {
        // Hazard guard: prior tile's ds_reads must retire before DMA overwrites LDS.
        asm volatile("s_waitcnt lgkmcnt(0)" ::: "memory");
        __builtin_amdgcn_wave_barrier();
        prefetch_tile(in, tg, t, lin, ltg, lane);     // 30 async DMAs, no VGPR payload
        asm volatile("s_waitcnt vmcnt(0)" ::: "memory");
        __builtin_amdgcn_wave_barrier();
        compute_tile(lin, ltg, lane, inv_gs, a_boxes, a_conf, a_class);
        __builtin_amdgcn_wave_barrier();
    }

    // ---- wave-64 shuffle reduce; one partial triple per WAVE ----
    #pragma unroll
    for (int off = 32; off > 0; off >>= 1) {
        a_boxes += __shfl_down(a_boxes, off, 64);
        a_conf  += __shfl_down(a_conf,  off, 64);
        a_class += __shfl_down(a_class, off, 64);
    }
    if (lane == 0) {
        ws[gwave]               = a_boxes;
        ws[gwave + pstride]     = a_conf;
        ws[gwave + 2 * pstride] = a_class;
    }
}

// ---------------- finalize: sum per-wave partials + remainder cells, scale, write out ----------------
__global__ __launch_bounds__(256) void yolo_finalize(
        const float* __restrict__ in,
        const float* __restrict__ tg,
        const float* __restrict__ ws, float* __restrict__ out,
        int nparts, int pstride, int rem_base, int rem, float inv_bs) {
    float b = 0.0f, c = 0.0f, k = 0.0f;
    for (int i = threadIdx.x; i < nparts; i += 256) {
        b += ws[i];
        c += ws[i + pstride];
        k += ws[i + 2 * pstride];
    }
    if ((int)threadIdx.x < rem) {
        const size_t cell = (size_t)(rem_base + threadIdx.x) * CC;
        cell_losses_global(in + cell, tg + cell, b, c, k);
    }
    #pragma unroll
    for (int off = 32; off > 0; off >>= 1) {
        b += __shfl_down(b, off, 64);
        c += __shfl_down(c, off, 64);
        k += __shfl_down(k, off, 64);
    }
    __shared__ float s_red[4][3];
    const int wave = threadIdx.x >> 6;
    if ((threadIdx.x & 63) == 0) {
        s_red[wave][0] = b;
        s_red[wave][1] = c;
        s_red[wave][2] = k;
    }
    __syncthreads();
    if (threadIdx.x == 0) {
        const float tb = s_red[0][0] + s_red[1][0] + s_red[2][0] + s_red[3][0];
        const float tc = s_red[0][1] + s_red[1][1] + s_red[2][1] + s_red[3][1];
        const float tk = s_red[0][2] + s_red[1][2] + s_red[2][2] + s_red[3][2];
        out[0] = 0.5f * tb * inv_bs;   // LAMBDA_COORD*(xy+wh)/bs
        out[1] = tc * inv_bs;          // (obj + 0.5*noobj)/bs
        out[2] = tk * inv_bs;          // class/bs
    }
}

extern "C" void kernel_launch(void* const* d_in, const int* in_sizes, int n_in,
                              void* d_out, int out_size, void* d_ws, size_t ws_size,
                              hipStream_t stream) {
    const float* in = (const float*)d_in[0];
    const float* tg = (const float*)d_in[1];
    float* out = (float*)d_out;
    float* ws  = (float*)d_ws;

    const int ncells = in_sizes[0] / CC;          // B * 49
    const int B = ncells / 49;
    const float inv_bs = 1.0f / (float)B;

    // 61.4 KB LDS/block (256 thr) -> 2 blocks/CU = 8 waves/CU, 512 blocks co-resident.
    const int nblocks = 512;
    const int nwaves  = nblocks * WPB;            // 2048
    const int pstride = nwaves;
    const int nfull   = ncells / TPW;
    const int rem     = ncells - nfull * TPW;     // 0 at B=8192

    yolo_main<<<nblocks, 256, 0, stream>>>(in, tg, ws, ncells, nwaves, pstride);
    yolo_finalize<<<1, 256, 0, stream>>>(in, tg, ws, out, nwaves, pstride,
                                         nfull * TPW, rem, inv_bs);
}